// Round 4
// baseline (76.809 us; speedup 1.0000x reference)
//
#include <hip/hip_runtime.h>
#include <hip/hip_bf16.h>
#include <stdint.h>

#define N_TOKENS    16384
#define MODEL_DIM   2048
#define NUM_EXPERTS 16
#define CAPACITY    2048
#define NBLK        256    // token blocks of 64
// d_out is FLOAT32. Element layout: [0]=l_aux, [1..32769)=weights[N][2],
// [32769..65537)=indices[E*CAP], [65537..98305)=expert_ids[E*CAP]
#define W_OFF       1
#define IDX_OFF     (1 + 2 * N_TOKENS)                  // 32769
#define EID_OFF     (IDX_OFF + NUM_EXPERTS * CAPACITY)  // 65537

// Scratch lives INSIDE d_out's expert_ids region (bytes [262148, 393220) =
// 131 KB; we use 49 KB). Read by k_prefix/k_laux/k_scatter/k_fill_idx, and
// clobbered only by the FINAL kernel k_eid. Same-stream serialization makes
// this race-free, and k_gate fully rewrites it each call (deterministic).
#define SCR_BYTE  (4 * EID_OFF)  // 262148, 4-aligned
#define SC_E01    0        // uint8  [16384]: e1 | (e2<<4)
#define SC_CNT    16384    // uint16 [16][256]
#define SC_START  24576    // uint16 [16][256]
#define SC_ME     32768    // float  [256][16]
#define SC_CE     49152    // int    [16]

// ============ K1: fused GEMV + softmax + top2 + counts + me ============
// 256 blocks x 256 thr. Block b: tokens [b*64, b*64+64). Wave q: dim slice.
// wg staged in LDS in two 1024-dim halves (64 KB); weight reads are
// wave-uniform broadcasts (lane = token).
__global__ __launch_bounds__(256) void k_gate(
    const float* __restrict__ x, const float* __restrict__ wg,
    float* __restrict__ out, uint8_t* __restrict__ scr)
{
  __shared__ float sw[NUM_EXPERTS * 1024];   // 64 KB
  const int tid = threadIdx.x;
  const int b = blockIdx.x;
  const int l = tid & 63;
  const int q = tid >> 6;
  const int t = b * 64 + l;

  float acc[NUM_EXPERTS];
#pragma unroll
  for (int e = 0; e < NUM_EXPERTS; e++) acc[e] = 0.f;

  for (int h = 0; h < 2; h++) {
    __syncthreads();   // h=1: wait for all readers of previous half
    // stage wg[:, h*1024 .. +1024): 4096 float4, 16 per thread, coalesced
    for (int i = tid; i < 4096; i += 256) {
      int e = i >> 8;          // 256 float4 per expert half-row
      int d4 = i & 255;
      float4 v = *reinterpret_cast<const float4*>(wg + e * MODEL_DIM + h * 1024 + d4 * 4);
      *reinterpret_cast<float4*>(&sw[e * 1024 + d4 * 4]) = v;
    }
    __syncthreads();

    const float4* xp = reinterpret_cast<const float4*>(
        x + (size_t)t * MODEL_DIM + h * 1024 + q * 256);
    const float* swq = &sw[q * 256];
#pragma unroll 2
    for (int j = 0; j < 64; j++) {
      float4 xv = xp[j];
#pragma unroll
      for (int e = 0; e < NUM_EXPERTS; e++) {
        float4 w = *reinterpret_cast<const float4*>(&swq[e * 1024 + j * 4]);  // broadcast
        acc[e] += xv.x * w.x + xv.y * w.y + xv.z * w.z + xv.w * w.w;
      }
    }
  }
  __syncthreads();   // all compute done before reusing sw

  // cross-wave partial reduce: sred[(q*64+l)] holds 16 floats
  float4* sred = reinterpret_cast<float4*>(sw);
#pragma unroll
  for (int e4 = 0; e4 < 4; e4++)
    sred[(q * 64 + l) * 4 + e4] =
        make_float4(acc[e4 * 4], acc[e4 * 4 + 1], acc[e4 * 4 + 2], acc[e4 * 4 + 3]);
  __syncthreads();

  if (tid < 64) {   // wave 0 finishes the block's 64 tokens
    float logit[NUM_EXPERTS];
#pragma unroll
    for (int e = 0; e < NUM_EXPERTS; e++) logit[e] = 0.f;
#pragma unroll
    for (int qq = 0; qq < 4; qq++) {
#pragma unroll
      for (int e4 = 0; e4 < 4; e4++) {
        float4 v = sred[(qq * 64 + l) * 4 + e4];
        logit[e4 * 4 + 0] += v.x; logit[e4 * 4 + 1] += v.y;
        logit[e4 * 4 + 2] += v.z; logit[e4 * 4 + 3] += v.w;
      }
    }
    float m = logit[0];
#pragma unroll
    for (int e = 1; e < NUM_EXPERTS; e++) m = fmaxf(m, logit[e]);
    float g[NUM_EXPERTS]; float z = 0.f;
#pragma unroll
    for (int e = 0; e < NUM_EXPERTS; e++) { g[e] = expf(logit[e] - m); z += g[e]; }
    float inv = 1.f / z;
#pragma unroll
    for (int e = 0; e < NUM_EXPERTS; e++) g[e] *= inv;

    // top-2, ties -> lower index (matches lax.top_k / argmax)
    float v1 = g[0], v2 = -1.f; int e1 = 0, e2 = 0;
#pragma unroll
    for (int e = 1; e < NUM_EXPERTS; e++) {
      if (g[e] > v1) { v2 = v1; e2 = e1; v1 = g[e]; e1 = e; }
      else if (g[e] > v2) { v2 = g[e]; e2 = e; }
    }
    out[W_OFF + 2 * t]     = v1;
    out[W_OFF + 2 * t + 1] = v2;
    scr[SC_E01 + t] = (uint8_t)(e1 | (e2 << 4));

    // per-block routed counts (token order preserved) + argmax count
    int mycount = 0, myce = 0;
    for (int e = 0; e < NUM_EXPERTS; e++) {
      unsigned long long m1 = __ballot(e1 == e);
      unsigned long long m2 = __ballot(e2 == e);
      if (l == e) { mycount = __popcll(m1 | m2); myce = __popcll(m1); }
    }
    if (l < NUM_EXPERTS) {
      reinterpret_cast<uint16_t*>(scr + SC_CNT)[l * NBLK + b] = (uint16_t)mycount;
      atomicAdd(reinterpret_cast<int*>(scr + SC_CE) + l, myce);
    }

    // me partial: butterfly over the 64 tokens
#pragma unroll
    for (int e = 0; e < NUM_EXPERTS; e++) {
#pragma unroll
      for (int off = 1; off < 64; off <<= 1) g[e] += __shfl_xor(g[e], off, 64);
    }
    if (l == 0) {
      float* mp = reinterpret_cast<float*>(scr + SC_ME);
#pragma unroll
      for (int e = 0; e < NUM_EXPERTS; e++) mp[b * NUM_EXPERTS + e] = g[e];
    }
  }
}

// ============ K2: per-expert exclusive prefix over 256 blocks ============
__global__ __launch_bounds__(256) void k_prefix(uint8_t* __restrict__ scr) {
  const uint16_t* counts = reinterpret_cast<const uint16_t*>(scr + SC_CNT);
  uint16_t* starts = reinterpret_cast<uint16_t*>(scr + SC_START);
  __shared__ int gs[NUM_EXPERTS][16];
  __shared__ int gstart[NUM_EXPERTS][17];
  const int tid = threadIdx.x;
  const int e = tid >> 4, grp = tid & 15;
  int s = 0;
  for (int c = grp * 16; c < grp * 16 + 16; c++) s += counts[e * NBLK + c];
  gs[e][grp] = s;
  __syncthreads();
  if (tid < NUM_EXPERTS) {
    int run = 0;
    for (int g2 = 0; g2 < 16; g2++) { gstart[tid][g2] = run; run += gs[tid][g2]; }
  }
  __syncthreads();
  int run = gstart[e][grp];
  for (int c = grp * 16; c < grp * 16 + 16; c++) {
    starts[e * NBLK + c] = (uint16_t)run;
    run += counts[e * NBLK + c];
  }
}

// ============ K3: l_aux ============
__global__ __launch_bounds__(64) void k_laux(
    const uint8_t* __restrict__ scr, float* __restrict__ out) {
  const float* mepart = reinterpret_cast<const float*>(scr + SC_ME);
  const int* cecnt = reinterpret_cast<const int*>(scr + SC_CE);
  const int lane = threadIdx.x;
  float prod = 0.f;
  if (lane < NUM_EXPERTS) {
    float s = 0.f;
    for (int b = 0; b < NBLK; b++) s += mepart[b * NUM_EXPERTS + lane];
    float me = s * (1.0f / N_TOKENS);
    float ce = (float)cecnt[lane] * (1.0f / N_TOKENS);
    prod = me * ce;
  }
#pragma unroll
  for (int off = 32; off > 0; off >>= 1) prod += __shfl_xor(prod, off, 64);
  if (lane == 0) out[0] = prod * (float)NUM_EXPERTS;
}

// ============ K4: scatter token ids into capacity table ============
__global__ __launch_bounds__(64) void k_scatter(
    const uint8_t* __restrict__ scr, float* __restrict__ out) {
  const uint16_t* starts = reinterpret_cast<const uint16_t*>(scr + SC_START);
  const int c = blockIdx.x;
  const int lane = threadIdx.x;
  const int t = c * 64 + lane;
  const int v = scr[SC_E01 + t];
  const int e1 = v & 15, e2 = v >> 4;
  const unsigned long long below = (1ull << lane) - 1ull;
  int p1 = CAPACITY, p2 = CAPACITY;
  for (int e = 0; e < NUM_EXPERTS; e++) {
    unsigned long long m = __ballot(e1 == e) | __ballot(e2 == e);
    int r = __popcll(m & below);
    int sbase = (int)starts[e * NBLK + c];
    if (e1 == e) p1 = sbase + r;
    if (e2 == e) p2 = sbase + r;
  }
  float tf = (float)t;   // exact in fp32
  if ((unsigned)p1 < (unsigned)CAPACITY) out[IDX_OFF + e1 * CAPACITY + p1] = tf;
  if ((unsigned)p2 < (unsigned)CAPACITY) out[IDX_OFF + e2 * CAPACITY + p2] = tf;
}

// ============ K5: fill -1 in empty index slots ============
__global__ __launch_bounds__(256) void k_fill_idx(
    const uint8_t* __restrict__ scr, float* __restrict__ out) {
  const uint16_t* counts = reinterpret_cast<const uint16_t*>(scr + SC_CNT);
  const uint16_t* starts = reinterpret_cast<const uint16_t*>(scr + SC_START);
  const int i = blockIdx.x * 256 + threadIdx.x;   // 0..32767
  const int e = i >> 11;
  const int p = i & (CAPACITY - 1);
  const int tot = (int)starts[e * NBLK + NBLK - 1] + (int)counts[e * NBLK + NBLK - 1];
  if (p >= tot) out[IDX_OFF + i] = -1.0f;
}

// ============ K6 (LAST — clobbers scratch): expert_ids ============
__global__ __launch_bounds__(256) void k_eid(float* __restrict__ out) {
  const int i = blockIdx.x * 256 + threadIdx.x;   // 0..32767
  out[EID_OFF + i] = (float)(i >> 11);
}

extern "C" void kernel_launch(void* const* d_in, const int* in_sizes, int n_in,
                              void* d_out, int out_size, void* d_ws, size_t ws_size,
                              hipStream_t stream) {
  const float* x  = (const float*)d_in[0];
  const float* wg = (const float*)d_in[1];
  float* out = (float*)d_out;
  uint8_t* scr = (uint8_t*)d_out + SCR_BYTE;   // inside expert_ids region
  (void)d_ws; (void)ws_size;

  hipMemsetAsync(scr + SC_CE, 0, NUM_EXPERTS * sizeof(int), stream);
  k_gate<<<NBLK, 256, 0, stream>>>(x, wg, out, scr);
  k_prefix<<<1, 256, 0, stream>>>(scr);
  k_laux<<<1, 64, 0, stream>>>(scr, out);
  k_scatter<<<NBLK, 64, 0, stream>>>(scr, out);
  k_fill_idx<<<128, 256, 0, stream>>>(scr, out);
  k_eid<<<128, 256, 0, stream>>>(out);
}